// Round 1
// baseline (328.096 us; speedup 1.0000x reference)
//
#include <hip/hip_runtime.h>

#define N_NODES 4096
#define N_EDGES 131072
#define DIM     256
#define HEADS   8
#define HDIM    32
#define MAXDEG  320

typedef unsigned short u16;
typedef unsigned int   u32;

using f32x4  = __attribute__((ext_vector_type(4))) float;
using bf16x8 = __attribute__((ext_vector_type(8))) short;
using u16x4  = __attribute__((ext_vector_type(4))) unsigned short;
using u16x8  = __attribute__((ext_vector_type(8))) unsigned short;

__device__ __forceinline__ u16 f2bf(float f) {
  u32 u = __float_as_uint(f);
  u += 0x7fffu + ((u >> 16) & 1u);   // RNE
  return (u16)(u >> 16);
}

// ---------------------------------------------------------------------------
// Weight prep: build transposed bf16 weights. WcatT = [Wq|Wk|Wv|Wi]^T (1024x256),
// WeT (256x256), WoT (256x256), bcat (1024).
// ---------------------------------------------------------------------------
__global__ __launch_bounds__(256) void prep_w_k(
    const float* __restrict__ Wq, const float* __restrict__ Wk,
    const float* __restrict__ Wv, const float* __restrict__ Wi,
    const float* __restrict__ We, const float* __restrict__ Wo,
    const float* __restrict__ bq, const float* __restrict__ bk,
    const float* __restrict__ bv, const float* __restrict__ bi,
    u16* __restrict__ WcatT, u16* __restrict__ WeT, u16* __restrict__ WoT,
    float* __restrict__ bcat)
{
  int n = blockIdx.x;
  int k = threadIdx.x;
  if (n < 1024) {
    const float* W = (n < 256) ? Wq : (n < 512) ? Wk : (n < 768) ? Wv : Wi;
    int nn = n & 255;
    WcatT[(size_t)n * 256 + k] = f2bf(W[(size_t)k * 256 + nn]);
    if (k == 0) {
      const float* b = (n < 256) ? bq : (n < 512) ? bk : (n < 768) ? bv : bi;
      bcat[n] = b[nn];
    }
  } else if (n < 1280) {
    int nn = n - 1024;
    WeT[(size_t)nn * 256 + k] = f2bf(We[(size_t)k * 256 + nn]);
  } else {
    int nn = n - 1280;
    WoT[(size_t)nn * 256 + k] = f2bf(Wo[(size_t)k * 256 + nn]);
  }
}

// ---------------------------------------------------------------------------
// GEMM: C[M x Nn] = A(fp32, M x 256) * B + bias, where BT (Nn x 256) is B^T in
// bf16. A converted to bf16 in-flight during LDS staging. 128x128 tile,
// 4 waves in 2x2, each wave 64x64 = 4x4 fragments of mfma_f32_16x16x32_bf16.
// grid = (Nn/128, M/128)  [x fastest => adjacent blocks share A rows -> L2]
// ---------------------------------------------------------------------------
__global__ __launch_bounds__(256) void gemm_rs_k(
    const float* __restrict__ Afp, const u16* __restrict__ BT,
    const float* __restrict__ bias, float* __restrict__ C, int M, int Nn)
{
  constexpr int K = 256;
  __shared__ u16 As[128 * 32];
  __shared__ u16 Bs[128 * 32];
  const int n0 = blockIdx.x * 128;
  const int m0 = blockIdx.y * 128;
  const int tid = threadIdx.x;
  const int w = tid >> 6, l = tid & 63;
  const int wr = w >> 1, wc = w & 1;
  const int fr = l & 15, hi = l >> 4;

  f32x4 acc[4][4] = {};

  for (int kt = 0; kt < K; kt += 32) {
    __syncthreads();   // previous iteration's frag reads complete
    // stage A: 128x32 fp32 tile -> bf16 LDS (row-major [128][32])
#pragma unroll
    for (int i = 0; i < 4; ++i) {
      int j = tid + 256 * i;            // float4 index 0..1023
      int row = j >> 3;                 // 8 float4 per row
      int col = (j & 7) << 2;
      float4 f = *(const float4*)(Afp + (size_t)(m0 + row) * K + kt + col);
      u16x4 u;
      u.x = f2bf(f.x); u.y = f2bf(f.y); u.z = f2bf(f.z); u.w = f2bf(f.w);
      *(u16x4*)&As[(size_t)j << 2] = u;
    }
    // stage B: 128x32 bf16 tile (rows of BT)
#pragma unroll
    for (int i = 0; i < 2; ++i) {
      int j = tid + 256 * i;            // 16B chunk index 0..511
      int row = j >> 2;
      int col = (j & 3) << 3;
      *(u16x8*)&Bs[(size_t)j << 3] =
          *(const u16x8*)(BT + (size_t)(n0 + row) * K + kt + col);
    }
    __syncthreads();

    bf16x8 a[4], b[4];
#pragma unroll
    for (int mi = 0; mi < 4; ++mi)
      a[mi] = *(const bf16x8*)&As[(wr * 64 + mi * 16 + fr) * 32 + hi * 8];
#pragma unroll
    for (int ni = 0; ni < 4; ++ni)
      b[ni] = *(const bf16x8*)&Bs[(wc * 64 + ni * 16 + fr) * 32 + hi * 8];
#pragma unroll
    for (int mi = 0; mi < 4; ++mi)
#pragma unroll
      for (int ni = 0; ni < 4; ++ni)
        acc[mi][ni] = __builtin_amdgcn_mfma_f32_16x16x32_bf16(
            a[mi], b[ni], acc[mi][ni], 0, 0, 0);
  }

  // epilogue: C/D layout col = lane&15, row = (lane>>4)*4 + reg
#pragma unroll
  for (int ni = 0; ni < 4; ++ni) {
    int col = n0 + wc * 64 + ni * 16 + fr;
    float bv = bias[col];
#pragma unroll
    for (int mi = 0; mi < 4; ++mi) {
      int row = m0 + wr * 64 + mi * 16 + hi * 4;
      f32x4 v = acc[mi][ni];
#pragma unroll
      for (int j = 0; j < 4; ++j)
        C[(size_t)(row + j) * Nn + col] = v[j] + bv;
    }
  }
}

// ---------------------------------------------------------------------------
// Per-edge attention logits: attn[e][h] = (Q[s]·K[t] + Q[s]·Ef[e] + Ef[e]·K[t]) / sqrt(32)
// 32 lanes per edge, 8 edges per block.
// ---------------------------------------------------------------------------
__global__ __launch_bounds__(256) void attn_edge_k(
    const float* __restrict__ QKVI, const float* __restrict__ Ef,
    const int* __restrict__ src, const int* __restrict__ tgt,
    float* __restrict__ attn)
{
  int gid = blockIdx.x * 256 + threadIdx.x;
  int e = gid >> 5;
  int d = gid & 31;
  if (e >= N_EDGES) return;
  int s = src[e], t = tgt[e];
  const float* q  = QKVI + (size_t)s * 1024;          // Q cols 0..255
  const float* k  = QKVI + (size_t)t * 1024 + 256;    // K cols 256..511
  const float* ef = Ef + (size_t)e * 256;
#pragma unroll
  for (int h = 0; h < HEADS; ++h) {
    float qv = q[h * 32 + d];
    float kv = k[h * 32 + d];
    float ev = ef[h * 32 + d];
    float v = qv * kv + qv * ev + ev * kv;
#pragma unroll
    for (int off = 16; off > 0; off >>= 1) v += __shfl_xor(v, off, 32);
    if (d == 0) attn[(size_t)e * 8 + h] = v * 0.17677669529663687f;
  }
}

// ---------------------------------------------------------------------------
// CSR build
// ---------------------------------------------------------------------------
__global__ __launch_bounds__(256) void hist_k(const int* __restrict__ src, int* __restrict__ deg)
{
  int e = blockIdx.x * 256 + threadIdx.x;
  if (e < N_EDGES) atomicAdd(&deg[src[e]], 1);
}

__global__ __launch_bounds__(1024) void scan_k(const int* __restrict__ deg,
                                               int* __restrict__ rowstart,
                                               int* __restrict__ cursor)
{
  __shared__ int s[1024];
  int tid = threadIdx.x;
  int4 v = ((const int4*)deg)[tid];
  int sum = v.x + v.y + v.z + v.w;
  s[tid] = sum;
  __syncthreads();
  for (int off = 1; off < 1024; off <<= 1) {
    int t = (tid >= off) ? s[tid - off] : 0;
    __syncthreads();
    s[tid] += t;
    __syncthreads();
  }
  int excl = s[tid] - sum;
  int r0 = excl, r1 = excl + v.x, r2 = r1 + v.y, r3 = r2 + v.z;
  rowstart[4 * tid + 0] = r0; cursor[4 * tid + 0] = r0;
  rowstart[4 * tid + 1] = r1; cursor[4 * tid + 1] = r1;
  rowstart[4 * tid + 2] = r2; cursor[4 * tid + 2] = r2;
  rowstart[4 * tid + 3] = r3; cursor[4 * tid + 3] = r3;
  if (tid == 1023) rowstart[4096] = r3 + v.w;
}

__global__ __launch_bounds__(256) void scatter_k(const int* __restrict__ src,
                                                 int* __restrict__ cursor,
                                                 int* __restrict__ csr)
{
  int e = blockIdx.x * 256 + threadIdx.x;
  if (e < N_EDGES) {
    int p = atomicAdd(&cursor[src[e]], 1);
    csr[p] = e;
  }
}

// ---------------------------------------------------------------------------
// Per-node sparse softmax + V aggregation. One block (256 thr) per node.
// Dedup: numpy last-write-wins => survivor = max edge id per (i,tgt);
// tgt==i edges dropped (diagonal overwritten by attn_self).
// ---------------------------------------------------------------------------
__global__ __launch_bounds__(256) void node_attn_k(
    const float* __restrict__ QKVI, const float* __restrict__ attn,
    const int* __restrict__ rowstart, const int* __restrict__ csr,
    const int* __restrict__ tgt, float* __restrict__ agg)
{
  __shared__ int   s_eid[MAXDEG];
  __shared__ int   s_tgt[MAXDEG];
  __shared__ float s_sc[MAXDEG * 8];
  __shared__ float s_w[MAXDEG * 8];
  __shared__ unsigned char s_alive[MAXDEG];
  __shared__ float s_self[8];
  __shared__ float s_wself[8];

  int i = blockIdx.x;
  int base = rowstart[i];
  int deg = rowstart[i + 1] - base;
  if (deg > MAXDEG) deg = MAXDEG;   // statistically impossible; safety
  int tid = threadIdx.x;

  for (int t = tid; t < deg; t += 256) {
    int e = csr[base + t];
    s_eid[t] = e;
    s_tgt[t] = tgt[e];
  }
  __syncthreads();

  // deterministic order: sort by edge id (deg ~ 32)
  if (tid == 0) {
    for (int a = 1; a < deg; ++a) {
      int e = s_eid[a], t2 = s_tgt[a];
      int b = a - 1;
      while (b >= 0 && s_eid[b] > e) { s_eid[b+1] = s_eid[b]; s_tgt[b+1] = s_tgt[b]; --b; }
      s_eid[b+1] = e; s_tgt[b+1] = t2;
    }
  }
  __syncthreads();

  // dedup (keep last = max eid), drop self-target
  for (int t = tid; t < deg; t += 256) {
    int tt = s_tgt[t];
    bool alive = (tt != i);
    if (alive)
      for (int u = t + 1; u < deg; ++u)
        if (s_tgt[u] == tt) { alive = false; break; }
    s_alive[t] = alive ? 1 : 0;
  }

  // self score: (Q[i,h]·K[i,h]) / sqrt(32)
  int h = tid >> 5, d = tid & 31;
  {
    float qv = QKVI[(size_t)i * 1024 + h * 32 + d];
    float kv = QKVI[(size_t)i * 1024 + 256 + h * 32 + d];
    float p = qv * kv;
#pragma unroll
    for (int off = 16; off > 0; off >>= 1) p += __shfl_xor(p, off, 32);
    if (d == 0) s_self[h] = p * 0.17677669529663687f;
  }

  // gather edge scores
  for (int idx = tid; idx < deg * 8; idx += 256)
    s_sc[idx] = attn[(size_t)s_eid[idx >> 3] * 8 + (idx & 7)];
  __syncthreads();

  // softmax per head (8 threads, deg ~32 serial — cheap)
  if (tid < 8) {
    int hh = tid;
    float m = s_self[hh];
    for (int t = 0; t < deg; ++t)
      if (s_alive[t]) m = fmaxf(m, s_sc[t * 8 + hh]);
    float wself = expf(s_self[hh] - m);
    float ssum = wself;
    for (int t = 0; t < deg; ++t) {
      float wv = s_alive[t] ? expf(s_sc[t * 8 + hh] - m) : 0.f;
      s_w[t * 8 + hh] = wv;
      ssum += wv;
    }
    float inv = 1.f / ssum;
    s_wself[hh] = wself * inv;
    for (int t = 0; t < deg; ++t) s_w[t * 8 + hh] *= inv;
  }
  __syncthreads();

  // aggregate V (cols 512..767 of QKVI)
  int col = h * 32 + d;
  float accv = s_wself[h] * QKVI[(size_t)i * 1024 + 512 + col];
  for (int t = 0; t < deg; ++t)
    if (s_alive[t])
      accv += s_w[t * 8 + h] * QKVI[(size_t)s_tgt[t] * 1024 + 512 + col];
  agg[(size_t)i * 256 + col] = accv;
}

// ---------------------------------------------------------------------------
// LayerNorm(x_proj + preo) -> node output
// ---------------------------------------------------------------------------
__global__ __launch_bounds__(256) void ln_k(
    const float* __restrict__ QKVI, const float* __restrict__ preo,
    const float* __restrict__ g, const float* __restrict__ b,
    float* __restrict__ out)
{
  int i = blockIdx.x, c = threadIdx.x;
  float v = QKVI[(size_t)i * 1024 + 768 + c] + preo[(size_t)i * 256 + c];
  float s1 = v, s2 = v * v;
#pragma unroll
  for (int off = 32; off > 0; off >>= 1) {
    s1 += __shfl_xor(s1, off, 64);
    s2 += __shfl_xor(s2, off, 64);
  }
  __shared__ float r1[4], r2[4];
  int w = c >> 6;
  if ((c & 63) == 0) { r1[w] = s1; r2[w] = s2; }
  __syncthreads();
  s1 = r1[0] + r1[1] + r1[2] + r1[3];
  s2 = r2[0] + r2[1] + r2[2] + r2[3];
  float mu  = s1 * (1.0f / 256.0f);
  float var = s2 * (1.0f / 256.0f) - mu * mu;
  out[(size_t)i * 256 + c] = (v - mu) * rsqrtf(var + 1e-5f) * g[c] + b[c];
}

// ---------------------------------------------------------------------------
extern "C" void kernel_launch(void* const* d_in, const int* in_sizes, int n_in,
                              void* d_out, int out_size, void* d_ws, size_t ws_size,
                              hipStream_t stream) {
  (void)in_sizes; (void)n_in; (void)out_size; (void)ws_size;
  const float* x  = (const float*)d_in[0];
  const int*   ei = (const int*)d_in[1];
  const float* ea = (const float*)d_in[2];
  const float* Wq = (const float*)d_in[3];  const float* bq = (const float*)d_in[4];
  const float* Wk = (const float*)d_in[5];  const float* bk = (const float*)d_in[6];
  const float* Wv = (const float*)d_in[7];  const float* bv = (const float*)d_in[8];
  const float* We = (const float*)d_in[9];  const float* be = (const float*)d_in[10];
  const float* Wo = (const float*)d_in[11]; const float* bo = (const float*)d_in[12];
  const float* Wi = (const float*)d_in[13]; const float* bi = (const float*)d_in[14];
  const float* lng = (const float*)d_in[15]; const float* lnb = (const float*)d_in[16];

  const int* src = ei;
  const int* tgt = ei + N_EDGES;

  char* ws = (char*)d_ws;
  u16*   WcatT   = (u16*)(ws + 0);              //   512 KB (1024 x 256 bf16)
  u16*   WeT     = (u16*)(ws + 524288);         //   128 KB
  u16*   WoT     = (u16*)(ws + 655360);         //   128 KB
  float* bcat    = (float*)(ws + 786432);       //     4 KB
  float* QKVI    = (float*)(ws + 790528);       //    16 MB (4096 x 1024)
  float* attn    = (float*)(ws + 17567744);     //     4 MB (E x 8)
  int*   deg     = (int*)(ws + 21762048);       //    16 KB
  int*   rowstart= (int*)(ws + 21778432);       //    16.25 KB (4097)
  int*   cursor  = (int*)(ws + 21795072);       //    16 KB
  int*   csr     = (int*)(ws + 21811456);       //   512 KB
  float* agg     = (float*)(ws + 22335744);     //     4 MB
  float* preo    = (float*)(ws + 26530048);     //     4 MB   -> total ~30.7 MB

  float* outN = (float*)d_out;                  // node_out (4096 x 256)
  float* outE = (float*)d_out + (size_t)N_NODES * DIM;  // edge_out / Efeat (E x 256)

  hipMemsetAsync(deg, 0, N_NODES * sizeof(int), stream);

  prep_w_k<<<1536, 256, 0, stream>>>(Wq, Wk, Wv, Wi, We, Wo, bq, bk, bv, bi,
                                     WcatT, WeT, WoT, bcat);

  // QKVI = x @ [Wq|Wk|Wv|Wi] + bcat   (M=4096, Nn=1024)
  gemm_rs_k<<<dim3(8, 32), 256, 0, stream>>>(x, WcatT, bcat, QKVI, N_NODES, 1024);

  // Efeat / edge_out = edge_attr @ We + be   (M=131072, Nn=256)
  gemm_rs_k<<<dim3(2, 1024), 256, 0, stream>>>(ea, WeT, be, outE, N_EDGES, 256);

  attn_edge_k<<<(N_EDGES * 32) / 256, 256, 0, stream>>>(QKVI, outE, src, tgt, attn);

  hist_k<<<N_EDGES / 256, 256, 0, stream>>>(src, deg);
  scan_k<<<1, 1024, 0, stream>>>(deg, rowstart, cursor);
  scatter_k<<<N_EDGES / 256, 256, 0, stream>>>(src, cursor, csr);

  node_attn_k<<<N_NODES, 256, 0, stream>>>(QKVI, attn, rowstart, csr, tgt, agg);

  // preo = agg @ Wo + bo   (M=4096, Nn=256)
  gemm_rs_k<<<dim3(2, 32), 256, 0, stream>>>(agg, WoT, bo, preo, N_NODES, 256);

  ln_k<<<N_NODES, 256, 0, stream>>>(QKVI, preo, lng, lnb, outN);
}

// Round 2
// 253.499 us; speedup vs baseline: 1.2943x; 1.2943x over previous
//
#include <hip/hip_runtime.h>

#define N_NODES 4096
#define N_EDGES 131072
#define DIM     256
#define HEADS   8
#define HDIM    32
#define MAXDEG  320
#define MAXDEGP 321   // +1 pad: (h*321+t)&31 varies with h -> no bank conflict

typedef unsigned short u16;
typedef unsigned int   u32;

using f32x4  = __attribute__((ext_vector_type(4))) float;
using bf16x8 = __attribute__((ext_vector_type(8))) short;
using u16x4  = __attribute__((ext_vector_type(4))) unsigned short;
using u16x8  = __attribute__((ext_vector_type(8))) unsigned short;

__device__ __forceinline__ u16 f2bf(float f) {
  u32 u = __float_as_uint(f);
  u += 0x7fffu + ((u >> 16) & 1u);   // RNE
  return (u16)(u >> 16);
}

// ---------------------------------------------------------------------------
// Weight prep: build transposed bf16 weights. WcatT = [Wq|Wk|Wv|Wi]^T (1024x256),
// WeT (256x256), WoT (256x256), bcat (1024).
// ---------------------------------------------------------------------------
__global__ __launch_bounds__(256) void prep_w_k(
    const float* __restrict__ Wq, const float* __restrict__ Wk,
    const float* __restrict__ Wv, const float* __restrict__ Wi,
    const float* __restrict__ We, const float* __restrict__ Wo,
    const float* __restrict__ bq, const float* __restrict__ bk,
    const float* __restrict__ bv, const float* __restrict__ bi,
    u16* __restrict__ WcatT, u16* __restrict__ WeT, u16* __restrict__ WoT,
    float* __restrict__ bcat)
{
  int n = blockIdx.x;
  int k = threadIdx.x;
  if (n < 1024) {
    const float* W = (n < 256) ? Wq : (n < 512) ? Wk : (n < 768) ? Wv : Wi;
    int nn = n & 255;
    WcatT[(size_t)n * 256 + k] = f2bf(W[(size_t)k * 256 + nn]);
    if (k == 0) {
      const float* b = (n < 256) ? bq : (n < 512) ? bk : (n < 768) ? bv : bi;
      bcat[n] = b[nn];
    }
  } else if (n < 1280) {
    int nn = n - 1024;
    WeT[(size_t)nn * 256 + k] = f2bf(We[(size_t)k * 256 + nn]);
  } else {
    int nn = n - 1280;
    WoT[(size_t)nn * 256 + k] = f2bf(Wo[(size_t)k * 256 + nn]);
  }
}

// ---------------------------------------------------------------------------
// GEMM: C[M x Nn] = A(fp32, M x 256) * B + bias, BT (Nn x 256) = B^T in bf16.
// A converted to bf16 in-flight during LDS staging. 128x128 tile, 4 waves 2x2,
// each wave 64x64 = 4x4 fragments of mfma_f32_16x16x32_bf16.
// ---------------------------------------------------------------------------
__global__ __launch_bounds__(256) void gemm_rs_k(
    const float* __restrict__ Afp, const u16* __restrict__ BT,
    const float* __restrict__ bias, float* __restrict__ C, int M, int Nn)
{
  constexpr int K = 256;
  __shared__ u16 As[128 * 32];
  __shared__ u16 Bs[128 * 32];
  const int n0 = blockIdx.x * 128;
  const int m0 = blockIdx.y * 128;
  const int tid = threadIdx.x;
  const int w = tid >> 6, l = tid & 63;
  const int wr = w >> 1, wc = w & 1;
  const int fr = l & 15, hi = l >> 4;

  f32x4 acc[4][4] = {};

  for (int kt = 0; kt < K; kt += 32) {
    __syncthreads();
#pragma unroll
    for (int i = 0; i < 4; ++i) {
      int j = tid + 256 * i;
      int row = j >> 3;
      int col = (j & 7) << 2;
      float4 f = *(const float4*)(Afp + (size_t)(m0 + row) * K + kt + col);
      u16x4 u;
      u.x = f2bf(f.x); u.y = f2bf(f.y); u.z = f2bf(f.z); u.w = f2bf(f.w);
      *(u16x4*)&As[(size_t)j << 2] = u;
    }
#pragma unroll
    for (int i = 0; i < 2; ++i) {
      int j = tid + 256 * i;
      int row = j >> 2;
      int col = (j & 3) << 3;
      *(u16x8*)&Bs[(size_t)j << 3] =
          *(const u16x8*)(BT + (size_t)(n0 + row) * K + kt + col);
    }
    __syncthreads();

    bf16x8 a[4], b[4];
#pragma unroll
    for (int mi = 0; mi < 4; ++mi)
      a[mi] = *(const bf16x8*)&As[(wr * 64 + mi * 16 + fr) * 32 + hi * 8];
#pragma unroll
    for (int ni = 0; ni < 4; ++ni)
      b[ni] = *(const bf16x8*)&Bs[(wc * 64 + ni * 16 + fr) * 32 + hi * 8];
#pragma unroll
    for (int mi = 0; mi < 4; ++mi)
#pragma unroll
      for (int ni = 0; ni < 4; ++ni)
        acc[mi][ni] = __builtin_amdgcn_mfma_f32_16x16x32_bf16(
            a[mi], b[ni], acc[mi][ni], 0, 0, 0);
  }

#pragma unroll
  for (int ni = 0; ni < 4; ++ni) {
    int col = n0 + wc * 64 + ni * 16 + fr;
    float bv = bias[col];
#pragma unroll
    for (int mi = 0; mi < 4; ++mi) {
      int row = m0 + wr * 64 + mi * 16 + hi * 4;
      f32x4 v = acc[mi][ni];
#pragma unroll
      for (int j = 0; j < 4; ++j)
        C[(size_t)(row + j) * Nn + col] = v[j] + bv;
    }
  }
}

// ---------------------------------------------------------------------------
// Per-edge attention logits
// ---------------------------------------------------------------------------
__global__ __launch_bounds__(256) void attn_edge_k(
    const float* __restrict__ QKVI, const float* __restrict__ Ef,
    const int* __restrict__ src, const int* __restrict__ tgt,
    float* __restrict__ attn)
{
  int gid = blockIdx.x * 256 + threadIdx.x;
  int e = gid >> 5;
  int d = gid & 31;
  if (e >= N_EDGES) return;
  int s = src[e], t = tgt[e];
  const float* q  = QKVI + (size_t)s * 1024;
  const float* k  = QKVI + (size_t)t * 1024 + 256;
  const float* ef = Ef + (size_t)e * 256;
#pragma unroll
  for (int h = 0; h < HEADS; ++h) {
    float qv = q[h * 32 + d];
    float kv = k[h * 32 + d];
    float ev = ef[h * 32 + d];
    float v = qv * kv + qv * ev + ev * kv;
#pragma unroll
    for (int off = 16; off > 0; off >>= 1) v += __shfl_xor(v, off, 32);
    if (d == 0) attn[(size_t)e * 8 + h] = v * 0.17677669529663687f;
  }
}

// ---------------------------------------------------------------------------
// CSR build
// ---------------------------------------------------------------------------
__global__ __launch_bounds__(256) void hist_k(const int* __restrict__ src, int* __restrict__ deg)
{
  int e = blockIdx.x * 256 + threadIdx.x;
  if (e < N_EDGES) atomicAdd(&deg[src[e]], 1);
}

__global__ __launch_bounds__(1024) void scan_k(const int* __restrict__ deg,
                                               int* __restrict__ rowstart,
                                               int* __restrict__ cursor)
{
  __shared__ int s[1024];
  int tid = threadIdx.x;
  int4 v = ((const int4*)deg)[tid];
  int sum = v.x + v.y + v.z + v.w;
  s[tid] = sum;
  __syncthreads();
  for (int off = 1; off < 1024; off <<= 1) {
    int t = (tid >= off) ? s[tid - off] : 0;
    __syncthreads();
    s[tid] += t;
    __syncthreads();
  }
  int excl = s[tid] - sum;
  int r0 = excl, r1 = excl + v.x, r2 = r1 + v.y, r3 = r2 + v.z;
  rowstart[4 * tid + 0] = r0; cursor[4 * tid + 0] = r0;
  rowstart[4 * tid + 1] = r1; cursor[4 * tid + 1] = r1;
  rowstart[4 * tid + 2] = r2; cursor[4 * tid + 2] = r2;
  rowstart[4 * tid + 3] = r3; cursor[4 * tid + 3] = r3;
  if (tid == 1023) rowstart[4096] = r3 + v.w;
}

__global__ __launch_bounds__(256) void scatter_k(const int* __restrict__ src,
                                                 int* __restrict__ cursor,
                                                 int* __restrict__ csr)
{
  int e = blockIdx.x * 256 + threadIdx.x;
  if (e < N_EDGES) {
    int p = atomicAdd(&cursor[src[e]], 1);
    csr[p] = e;
  }
}

// ---------------------------------------------------------------------------
// Per-node sparse softmax + V aggregation. One block (256 thr) per node.
// Dedup: numpy last-write-wins => survivor = max edge id per (i,tgt), done
// WITHOUT sorting (order-independent predicate). Softmax: 32 lanes per head.
// ---------------------------------------------------------------------------
__global__ __launch_bounds__(256) void node_attn_k(
    const float* __restrict__ QKVI, const float* __restrict__ attn,
    const int* __restrict__ rowstart, const int* __restrict__ csr,
    const int* __restrict__ tgt, float* __restrict__ agg)
{
  __shared__ int   s_eid[MAXDEG];
  __shared__ int   s_tgt[MAXDEG];
  __shared__ float s_sc[HEADS][MAXDEGP];
  __shared__ float s_w[HEADS][MAXDEGP];
  __shared__ unsigned char s_alive[MAXDEG];
  __shared__ float s_self[8];
  __shared__ float s_wself[8];

  int i = blockIdx.x;
  int base = rowstart[i];
  int deg = rowstart[i + 1] - base;
  if (deg > MAXDEG) deg = MAXDEG;
  int tid = threadIdx.x;
  int h = tid >> 5, d = tid & 31;

  for (int t = tid; t < deg; t += 256) {
    int e = csr[base + t];
    s_eid[t] = e;
    s_tgt[t] = tgt[e];
  }
  __syncthreads();

  // dedup (keep max eid per tgt), drop self-target — parallel, no sort
  for (int t = tid; t < deg; t += 256) {
    int tt = s_tgt[t], ee = s_eid[t];
    bool alive = (tt != i);
    if (alive)
      for (int u = 0; u < deg; ++u)
        if (s_tgt[u] == tt && s_eid[u] > ee) { alive = false; break; }
    s_alive[t] = alive ? 1 : 0;
  }

  // self score: (Q[i,h]·K[i,h]) / sqrt(32)
  {
    float qv = QKVI[(size_t)i * 1024 + h * 32 + d];
    float kv = QKVI[(size_t)i * 1024 + 256 + h * 32 + d];
    float p = qv * kv;
#pragma unroll
    for (int off = 16; off > 0; off >>= 1) p += __shfl_xor(p, off, 32);
    if (d == 0) s_self[h] = p * 0.17677669529663687f;
  }

  // gather edge scores, transposed to [h][t]
  for (int idx = tid; idx < deg * 8; idx += 256) {
    int t = idx >> 3, hh = idx & 7;
    s_sc[hh][t] = attn[(size_t)s_eid[t] * 8 + hh];
  }
  __syncthreads();

  // softmax: 32 lanes per head, shuffle reductions
  {
    float m = s_self[h];
    for (int t = d; t < deg; t += 32)
      if (s_alive[t]) m = fmaxf(m, s_sc[h][t]);
#pragma unroll
    for (int off = 16; off > 0; off >>= 1) m = fmaxf(m, __shfl_xor(m, off, 32));
    float lsum = 0.f;
    for (int t = d; t < deg; t += 32) {
      float wv = s_alive[t] ? expf(s_sc[h][t] - m) : 0.f;
      s_w[h][t] = wv;
      lsum += wv;
    }
#pragma unroll
    for (int off = 16; off > 0; off >>= 1) lsum += __shfl_xor(lsum, off, 32);
    float wself = expf(s_self[h] - m);
    float inv = 1.f / (lsum + wself);
    if (d == 0) s_wself[h] = wself * inv;
    for (int t = d; t < deg; t += 32) s_w[h][t] *= inv;
  }
  __syncthreads();

  // aggregate V (cols 512..767 of QKVI)
  int col = h * 32 + d;
  float accv = s_wself[h] * QKVI[(size_t)i * 1024 + 512 + col];
  for (int t = 0; t < deg; ++t)
    if (s_alive[t])
      accv += s_w[h][t] * QKVI[(size_t)s_tgt[t] * 1024 + 512 + col];
  agg[(size_t)i * 256 + col] = accv;
}

// ---------------------------------------------------------------------------
// LayerNorm(x_proj + preo) -> node output
// ---------------------------------------------------------------------------
__global__ __launch_bounds__(256) void ln_k(
    const float* __restrict__ QKVI, const float* __restrict__ preo,
    const float* __restrict__ g, const float* __restrict__ b,
    float* __restrict__ out)
{
  int i = blockIdx.x, c = threadIdx.x;
  float v = QKVI[(size_t)i * 1024 + 768 + c] + preo[(size_t)i * 256 + c];
  float s1 = v, s2 = v * v;
#pragma unroll
  for (int off = 32; off > 0; off >>= 1) {
    s1 += __shfl_xor(s1, off, 64);
    s2 += __shfl_xor(s2, off, 64);
  }
  __shared__ float r1[4], r2[4];
  int w = c >> 6;
  if ((c & 63) == 0) { r1[w] = s1; r2[w] = s2; }
  __syncthreads();
  s1 = r1[0] + r1[1] + r1[2] + r1[3];
  s2 = r2[0] + r2[1] + r2[2] + r2[3];
  float mu  = s1 * (1.0f / 256.0f);
  float var = s2 * (1.0f / 256.0f) - mu * mu;
  out[(size_t)i * 256 + c] = (v - mu) * rsqrtf(var + 1e-5f) * g[c] + b[c];
}

// ---------------------------------------------------------------------------
extern "C" void kernel_launch(void* const* d_in, const int* in_sizes, int n_in,
                              void* d_out, int out_size, void* d_ws, size_t ws_size,
                              hipStream_t stream) {
  (void)in_sizes; (void)n_in; (void)out_size; (void)ws_size;
  const float* x  = (const float*)d_in[0];
  const int*   ei = (const int*)d_in[1];
  const float* ea = (const float*)d_in[2];
  const float* Wq = (const float*)d_in[3];  const float* bq = (const float*)d_in[4];
  const float* Wk = (const float*)d_in[5];  const float* bk = (const float*)d_in[6];
  const float* Wv = (const float*)d_in[7];  const float* bv = (const float*)d_in[8];
  const float* We = (const float*)d_in[9];  const float* be = (const float*)d_in[10];
  const float* Wo = (const float*)d_in[11]; const float* bo = (const float*)d_in[12];
  const float* Wi = (const float*)d_in[13]; const float* bi = (const float*)d_in[14];
  const float* lng = (const float*)d_in[15]; const float* lnb = (const float*)d_in[16];

  const int* src = ei;
  const int* tgt = ei + N_EDGES;

  char* ws = (char*)d_ws;
  u16*   WcatT   = (u16*)(ws + 0);
  u16*   WeT     = (u16*)(ws + 524288);
  u16*   WoT     = (u16*)(ws + 655360);
  float* bcat    = (float*)(ws + 786432);
  float* QKVI    = (float*)(ws + 790528);
  float* attn    = (float*)(ws + 17567744);
  int*   deg     = (int*)(ws + 21762048);
  int*   rowstart= (int*)(ws + 21778432);
  int*   cursor  = (int*)(ws + 21795072);
  int*   csr     = (int*)(ws + 21811456);
  float* agg     = (float*)(ws + 22335744);
  float* preo    = (float*)(ws + 26530048);

  float* outN = (float*)d_out;
  float* outE = (float*)d_out + (size_t)N_NODES * DIM;

  hipMemsetAsync(deg, 0, N_NODES * sizeof(int), stream);

  prep_w_k<<<1536, 256, 0, stream>>>(Wq, Wk, Wv, Wi, We, Wo, bq, bk, bv, bi,
                                     WcatT, WeT, WoT, bcat);

  gemm_rs_k<<<dim3(8, 32), 256, 0, stream>>>(x, WcatT, bcat, QKVI, N_NODES, 1024);

  gemm_rs_k<<<dim3(2, 1024), 256, 0, stream>>>(ea, WeT, be, outE, N_EDGES, 256);

  attn_edge_k<<<(N_EDGES * 32) / 256, 256, 0, stream>>>(QKVI, outE, src, tgt, attn);

  hist_k<<<N_EDGES / 256, 256, 0, stream>>>(src, deg);
  scan_k<<<1, 1024, 0, stream>>>(deg, rowstart, cursor);
  scatter_k<<<N_EDGES / 256, 256, 0, stream>>>(src, cursor, csr);

  node_attn_k<<<N_NODES, 256, 0, stream>>>(QKVI, attn, rowstart, csr, tgt, agg);

  gemm_rs_k<<<dim3(2, 32), 256, 0, stream>>>(agg, WoT, bo, preo, N_NODES, 256);

  ln_k<<<N_NODES, 256, 0, stream>>>(QKVI, preo, lng, lnb, outN);
}

// Round 3
// 240.734 us; speedup vs baseline: 1.3629x; 1.0530x over previous
//
#include <hip/hip_runtime.h>

#define N_NODES 4096
#define N_EDGES 131072
#define DIM     256
#define HEADS   8
#define HDIM    32
#define MAXDEG  320
#define MAXDEGP 321

typedef unsigned short u16;
typedef unsigned int   u32;

using f32x4  = __attribute__((ext_vector_type(4))) float;
using bf16x8 = __attribute__((ext_vector_type(8))) short;
using u16x4  = __attribute__((ext_vector_type(4))) unsigned short;
using u16x8  = __attribute__((ext_vector_type(8))) unsigned short;

__device__ __forceinline__ u16 f2bf(float f) {
  u32 u = __float_as_uint(f);
  u += 0x7fffu + ((u >> 16) & 1u);   // RNE
  return (u16)(u >> 16);
}

// ---------------------------------------------------------------------------
// Weight prep
// ---------------------------------------------------------------------------
__global__ __launch_bounds__(256) void prep_w_k(
    const float* __restrict__ Wq, const float* __restrict__ Wk,
    const float* __restrict__ Wv, const float* __restrict__ Wi,
    const float* __restrict__ We, const float* __restrict__ Wo,
    const float* __restrict__ bq, const float* __restrict__ bk,
    const float* __restrict__ bv, const float* __restrict__ bi,
    u16* __restrict__ WcatT, u16* __restrict__ WeT, u16* __restrict__ WoT,
    float* __restrict__ bcat)
{
  int n = blockIdx.x;
  int k = threadIdx.x;
  if (n < 1024) {
    const float* W = (n < 256) ? Wq : (n < 512) ? Wk : (n < 768) ? Wv : Wi;
    int nn = n & 255;
    WcatT[(size_t)n * 256 + k] = f2bf(W[(size_t)k * 256 + nn]);
    if (k == 0) {
      const float* b = (n < 256) ? bq : (n < 512) ? bk : (n < 768) ? bv : bi;
      bcat[n] = b[nn];
    }
  } else if (n < 1280) {
    int nn = n - 1024;
    WeT[(size_t)nn * 256 + k] = f2bf(We[(size_t)k * 256 + nn]);
  } else {
    int nn = n - 1280;
    WoT[(size_t)nn * 256 + k] = f2bf(Wo[(size_t)k * 256 + nn]);
  }
}

// ---------------------------------------------------------------------------
// GEMM: C[M x Nn] = A(fp32, M x 256) @ B + bias. BT (Nn x 256) = B^T bf16.
// 128x128 tile, 4 waves 2x2, mfma_f32_16x16x32_bf16, K=256 in 8 steps of 32.
// Double-buffered LDS, reg-prefetch one step ahead, lgkmcnt-only barrier
// (no vmcnt drain in loop). 16B-chunk XOR swizzle kills 8-way read conflict.
// FUSE: also compute attn logits (Ef*(Q+K)+Q*K per head) in epilogue.
// ---------------------------------------------------------------------------
template<bool FUSE>
__global__ __launch_bounds__(256) void gemm2_k(
    const float* __restrict__ Afp, const u16* __restrict__ BT,
    const float* __restrict__ bias, float* __restrict__ C, int Nn,
    const int* __restrict__ src, const int* __restrict__ tgt,
    const float* __restrict__ QKVI, float* __restrict__ attn)
{
  __shared__ u16 As[2][128 * 32];
  __shared__ u16 Bs[2][128 * 32];
  const int n0 = blockIdx.x * 128;
  const int m0 = blockIdx.y * 128;
  const int tid = threadIdx.x;
  const int w = tid >> 6, l = tid & 63;
  const int wr = w >> 1, wc = w & 1;
  const int fr = l & 15, hi = l >> 4;

  float4 pa[4];
  u16x8  pb[2];
  f32x4  acc[4][4] = {};

  auto loadstep = [&](int kt) {
#pragma unroll
    for (int i = 0; i < 4; ++i) {
      int j = tid + 256 * i;
      pa[i] = *(const float4*)(Afp + (size_t)(m0 + (j >> 3)) * 256 + kt * 32 + ((j & 7) << 2));
    }
#pragma unroll
    for (int i = 0; i < 2; ++i) {
      int j = tid + 256 * i;
      pb[i] = *(const u16x8*)(BT + (size_t)(n0 + (j >> 2)) * 256 + kt * 32 + ((j & 3) << 3));
    }
  };
  auto storestep = [&](int buf) {
#pragma unroll
    for (int i = 0; i < 4; ++i) {
      int j = tid + 256 * i;
      int row = j >> 3;
      int c16 = (j & 7) >> 1, half = j & 1;
      int swc = (c16 + ((row >> 1) & 3)) & 3;
      u16x4 u;
      u.x = f2bf(pa[i].x); u.y = f2bf(pa[i].y); u.z = f2bf(pa[i].z); u.w = f2bf(pa[i].w);
      *(u16x4*)&As[buf][row * 32 + swc * 8 + half * 4] = u;
    }
#pragma unroll
    for (int i = 0; i < 2; ++i) {
      int j = tid + 256 * i;
      int row = j >> 2;
      int swc = ((j & 3) + ((row >> 1) & 3)) & 3;
      *(u16x8*)&Bs[buf][row * 32 + swc * 8] = pb[i];
    }
  };

  loadstep(0);
  storestep(0);

#pragma unroll
  for (int kt = 0; kt < 8; ++kt) {
    if (kt < 7) loadstep(kt + 1);
    __builtin_amdgcn_sched_barrier(0);
    asm volatile("s_waitcnt lgkmcnt(0)" ::: "memory");
    __builtin_amdgcn_s_barrier();
    __builtin_amdgcn_sched_barrier(0);
    const int cur = kt & 1;
    bf16x8 a[4], b[4];
#pragma unroll
    for (int mi = 0; mi < 4; ++mi) {
      int rA = wr * 64 + mi * 16 + fr;
      int swc = (hi + ((rA >> 1) & 3)) & 3;
      a[mi] = *(const bf16x8*)&As[cur][rA * 32 + swc * 8];
    }
#pragma unroll
    for (int ni = 0; ni < 4; ++ni) {
      int rB = wc * 64 + ni * 16 + fr;
      int swc = (hi + ((rB >> 1) & 3)) & 3;
      b[ni] = *(const bf16x8*)&Bs[cur][rB * 32 + swc * 8];
    }
#pragma unroll
    for (int mi = 0; mi < 4; ++mi)
#pragma unroll
      for (int ni = 0; ni < 4; ++ni)
        acc[mi][ni] = __builtin_amdgcn_mfma_f32_16x16x32_bf16(
            a[mi], b[ni], acc[mi][ni], 0, 0, 0);
    if (kt < 7) storestep((kt + 1) & 1);
  }

  // C write
#pragma unroll
  for (int ni = 0; ni < 4; ++ni) {
    int col = n0 + wc * 64 + ni * 16 + fr;
    float bv = bias[col];
#pragma unroll
    for (int mi = 0; mi < 4; ++mi) {
      int row = m0 + wr * 64 + mi * 16 + hi * 4;
      f32x4 v = acc[mi][ni];
#pragma unroll
      for (int j = 0; j < 4; ++j)
        C[(size_t)(row + j) * Nn + col] = v[j] + bv;
    }
  }

  if constexpr (FUSE) {
    // attn[e][h] = sum_d Ef*(Q_src+K_tgt)+Q_src*K_tgt over head dims, /sqrt(32)
    const float scl = 0.17677669529663687f;
#pragma unroll
    for (int mi = 0; mi < 4; ++mi) {
#pragma unroll
      for (int j = 0; j < 4; ++j) {
        int e = m0 + wr * 64 + mi * 16 + hi * 4 + j;
        int s = src[e], t = tgt[e];
        float sum0 = 0.f, sum1 = 0.f;
#pragma unroll
        for (int ni = 0; ni < 4; ++ni) {
          int gcol = n0 + wc * 64 + ni * 16 + fr;
          float ef = acc[mi][ni][j] + bias[gcol];
          float qv = QKVI[(size_t)s * 1024 + gcol];
          float kv = QKVI[(size_t)t * 1024 + 256 + gcol];
          float v = ef * (qv + kv) + qv * kv;
          if (ni < 2) sum0 += v; else sum1 += v;
        }
#pragma unroll
        for (int off = 1; off <= 8; off <<= 1) {
          sum0 += __shfl_xor(sum0, off);
          sum1 += __shfl_xor(sum1, off);
        }
        if (fr == 0) {
          int h0 = (n0 >> 5) + wc * 2;
          attn[(size_t)e * 8 + h0]     = sum0 * scl;
          attn[(size_t)e * 8 + h0 + 1] = sum1 * scl;
        }
      }
    }
  }
}

// ---------------------------------------------------------------------------
// CSR build
// ---------------------------------------------------------------------------
__global__ __launch_bounds__(256) void hist_k(const int* __restrict__ src, int* __restrict__ deg)
{
  int e = blockIdx.x * 256 + threadIdx.x;
  if (e < N_EDGES) atomicAdd(&deg[src[e]], 1);
}

__global__ __launch_bounds__(1024) void scan_k(const int* __restrict__ deg,
                                               int* __restrict__ rowstart,
                                               int* __restrict__ cursor)
{
  __shared__ int s[1024];
  int tid = threadIdx.x;
  int4 v = ((const int4*)deg)[tid];
  int sum = v.x + v.y + v.z + v.w;
  s[tid] = sum;
  __syncthreads();
  for (int off = 1; off < 1024; off <<= 1) {
    int t = (tid >= off) ? s[tid - off] : 0;
    __syncthreads();
    s[tid] += t;
    __syncthreads();
  }
  int excl = s[tid] - sum;
  int r0 = excl, r1 = excl + v.x, r2 = r1 + v.y, r3 = r2 + v.z;
  rowstart[4 * tid + 0] = r0; cursor[4 * tid + 0] = r0;
  rowstart[4 * tid + 1] = r1; cursor[4 * tid + 1] = r1;
  rowstart[4 * tid + 2] = r2; cursor[4 * tid + 2] = r2;
  rowstart[4 * tid + 3] = r3; cursor[4 * tid + 3] = r3;
  if (tid == 1023) rowstart[4096] = r3 + v.w;
}

__global__ __launch_bounds__(256) void scatter_k(const int* __restrict__ src,
                                                 int* __restrict__ cursor,
                                                 int* __restrict__ csr)
{
  int e = blockIdx.x * 256 + threadIdx.x;
  if (e < N_EDGES) {
    int p = atomicAdd(&cursor[src[e]], 1);
    csr[p] = e;
  }
}

// ---------------------------------------------------------------------------
// Per-node sparse softmax + V aggregation
// ---------------------------------------------------------------------------
__global__ __launch_bounds__(256) void node_attn_k(
    const float* __restrict__ QKVI, const float* __restrict__ attn,
    const int* __restrict__ rowstart, const int* __restrict__ csr,
    const int* __restrict__ tgt, float* __restrict__ agg)
{
  __shared__ int   s_eid[MAXDEG];
  __shared__ int   s_tgt[MAXDEG];
  __shared__ float s_sc[HEADS][MAXDEGP];
  __shared__ float s_w[HEADS][MAXDEGP];
  __shared__ unsigned char s_alive[MAXDEG];
  __shared__ float s_self[8];
  __shared__ float s_wself[8];

  int i = blockIdx.x;
  int base = rowstart[i];
  int deg = rowstart[i + 1] - base;
  if (deg > MAXDEG) deg = MAXDEG;
  int tid = threadIdx.x;
  int h = tid >> 5, d = tid & 31;

  for (int t = tid; t < deg; t += 256) {
    int e = csr[base + t];
    s_eid[t] = e;
    s_tgt[t] = tgt[e];
  }
  __syncthreads();

  for (int t = tid; t < deg; t += 256) {
    int tt = s_tgt[t], ee = s_eid[t];
    bool alive = (tt != i);
    if (alive)
      for (int u = 0; u < deg; ++u)
        if (s_tgt[u] == tt && s_eid[u] > ee) { alive = false; break; }
    s_alive[t] = alive ? 1 : 0;
  }

  {
    float qv = QKVI[(size_t)i * 1024 + h * 32 + d];
    float kv = QKVI[(size_t)i * 1024 + 256 + h * 32 + d];
    float p = qv * kv;
#pragma unroll
    for (int off = 16; off > 0; off >>= 1) p += __shfl_xor(p, off, 32);
    if (d == 0) s_self[h] = p * 0.17677669529663687f;
  }

  for (int idx = tid; idx < deg * 8; idx += 256) {
    int t = idx >> 3, hh = idx & 7;
    s_sc[hh][t] = attn[(size_t)s_eid[t] * 8 + hh];
  }
  __syncthreads();

  {
    float m = s_self[h];
    for (int t = d; t < deg; t += 32)
      if (s_alive[t]) m = fmaxf(m, s_sc[h][t]);
#pragma unroll
    for (int off = 16; off > 0; off >>= 1) m = fmaxf(m, __shfl_xor(m, off, 32));
    float lsum = 0.f;
    for (int t = d; t < deg; t += 32) {
      float wv = s_alive[t] ? expf(s_sc[h][t] - m) : 0.f;
      s_w[h][t] = wv;
      lsum += wv;
    }
#pragma unroll
    for (int off = 16; off > 0; off >>= 1) lsum += __shfl_xor(lsum, off, 32);
    float wself = expf(s_self[h] - m);
    float inv = 1.f / (lsum + wself);
    if (d == 0) s_wself[h] = wself * inv;
    for (int t = d; t < deg; t += 32) s_w[h][t] *= inv;
  }
  __syncthreads();

  int col = h * 32 + d;
  float accv = s_wself[h] * QKVI[(size_t)i * 1024 + 512 + col];
  for (int t = 0; t < deg; ++t)
    if (s_alive[t])
      accv += s_w[h][t] * QKVI[(size_t)s_tgt[t] * 1024 + 512 + col];
  agg[(size_t)i * 256 + col] = accv;
}

// ---------------------------------------------------------------------------
// LayerNorm(x_proj + preo)
// ---------------------------------------------------------------------------
__global__ __launch_bounds__(256) void ln_k(
    const float* __restrict__ QKVI, const float* __restrict__ preo,
    const float* __restrict__ g, const float* __restrict__ b,
    float* __restrict__ out)
{
  int i = blockIdx.x, c = threadIdx.x;
  float v = QKVI[(size_t)i * 1024 + 768 + c] + preo[(size_t)i * 256 + c];
  float s1 = v, s2 = v * v;
#pragma unroll
  for (int off = 32; off > 0; off >>= 1) {
    s1 += __shfl_xor(s1, off, 64);
    s2 += __shfl_xor(s2, off, 64);
  }
  __shared__ float r1[4], r2[4];
  int w = c >> 6;
  if ((c & 63) == 0) { r1[w] = s1; r2[w] = s2; }
  __syncthreads();
  s1 = r1[0] + r1[1] + r1[2] + r1[3];
  s2 = r2[0] + r2[1] + r2[2] + r2[3];
  float mu  = s1 * (1.0f / 256.0f);
  float var = s2 * (1.0f / 256.0f) - mu * mu;
  out[(size_t)i * 256 + c] = (v - mu) * rsqrtf(var + 1e-5f) * g[c] + b[c];
}

// ---------------------------------------------------------------------------
extern "C" void kernel_launch(void* const* d_in, const int* in_sizes, int n_in,
                              void* d_out, int out_size, void* d_ws, size_t ws_size,
                              hipStream_t stream) {
  (void)in_sizes; (void)n_in; (void)out_size; (void)ws_size;
  const float* x  = (const float*)d_in[0];
  const int*   ei = (const int*)d_in[1];
  const float* ea = (const float*)d_in[2];
  const float* Wq = (const float*)d_in[3];  const float* bq = (const float*)d_in[4];
  const float* Wk = (const float*)d_in[5];  const float* bk = (const float*)d_in[6];
  const float* Wv = (const float*)d_in[7];  const float* bv = (const float*)d_in[8];
  const float* We = (const float*)d_in[9];  const float* be = (const float*)d_in[10];
  const float* Wo = (const float*)d_in[11]; const float* bo = (const float*)d_in[12];
  const float* Wi = (const float*)d_in[13]; const float* bi = (const float*)d_in[14];
  const float* lng = (const float*)d_in[15]; const float* lnb = (const float*)d_in[16];

  const int* src = ei;
  const int* tgt = ei + N_EDGES;

  char* ws = (char*)d_ws;
  u16*   WcatT   = (u16*)(ws + 0);
  u16*   WeT     = (u16*)(ws + 524288);
  u16*   WoT     = (u16*)(ws + 655360);
  float* bcat    = (float*)(ws + 786432);
  float* QKVI    = (float*)(ws + 790528);
  float* attn    = (float*)(ws + 17567744);
  int*   deg     = (int*)(ws + 21762048);
  int*   rowstart= (int*)(ws + 21778432);
  int*   cursor  = (int*)(ws + 21795072);
  int*   csr     = (int*)(ws + 21811456);
  float* agg     = (float*)(ws + 22335744);
  float* preo    = (float*)(ws + 26530048);

  float* outN = (float*)d_out;
  float* outE = (float*)d_out + (size_t)N_NODES * DIM;

  hipMemsetAsync(deg, 0, N_NODES * sizeof(int), stream);

  prep_w_k<<<1536, 256, 0, stream>>>(Wq, Wk, Wv, Wi, We, Wo, bq, bk, bv, bi,
                                     WcatT, WeT, WoT, bcat);

  // QKVI = x @ [Wq|Wk|Wv|Wi] + bcat
  gemm2_k<false><<<dim3(8, 32), 256, 0, stream>>>(
      x, WcatT, bcat, QKVI, 1024, nullptr, nullptr, nullptr, nullptr);

  // edge_out = edge_attr @ We + be, fused with attn-logit computation
  gemm2_k<true><<<dim3(2, 1024), 256, 0, stream>>>(
      ea, WeT, be, outE, 256, src, tgt, QKVI, attn);

  hist_k<<<N_EDGES / 256, 256, 0, stream>>>(src, deg);
  scan_k<<<1, 1024, 0, stream>>>(deg, rowstart, cursor);
  scatter_k<<<N_EDGES / 256, 256, 0, stream>>>(src, cursor, csr);

  node_attn_k<<<N_NODES, 256, 0, stream>>>(QKVI, attn, rowstart, csr, tgt, agg);

  // preo = agg @ Wo + bo
  gemm2_k<false><<<dim3(2, 32), 256, 0, stream>>>(
      agg, WoT, bo, preo, 256, nullptr, nullptr, nullptr, nullptr);

  ln_k<<<N_NODES, 256, 0, stream>>>(QKVI, preo, lng, lnb, outN);
}

// Round 4
// 219.547 us; speedup vs baseline: 1.4944x; 1.0965x over previous
//
#include <hip/hip_runtime.h>

#define N_NODES 4096
#define N_EDGES 131072
#define DIM     256
#define HEADS   8
#define HDIM    32
#define MAXDEG  320
#define MAXDEGP 321

typedef unsigned short u16;
typedef unsigned int   u32;

using f32x4  = __attribute__((ext_vector_type(4))) float;
using bf16x8 = __attribute__((ext_vector_type(8))) short;
using u16x4  = __attribute__((ext_vector_type(4))) unsigned short;
using u16x8  = __attribute__((ext_vector_type(8))) unsigned short;

__device__ __forceinline__ u16 f2bf(float f) {
  u32 u = __float_as_uint(f);
  u += 0x7fffu + ((u >> 16) & 1u);   // RNE
  return (u16)(u >> 16);
}

__device__ __forceinline__ float dot4(float4 a, float4 b) {
  return a.x * b.x + a.y * b.y + a.z * b.z + a.w * b.w;
}

// ---------------------------------------------------------------------------
// Weight prep
// ---------------------------------------------------------------------------
__global__ __launch_bounds__(256) void prep_w_k(
    const float* __restrict__ Wq, const float* __restrict__ Wk,
    const float* __restrict__ Wv, const float* __restrict__ Wi,
    const float* __restrict__ We, const float* __restrict__ Wo,
    const float* __restrict__ bq, const float* __restrict__ bk,
    const float* __restrict__ bv, const float* __restrict__ bi,
    u16* __restrict__ WcatT, u16* __restrict__ WeT, u16* __restrict__ WoT,
    float* __restrict__ bcat)
{
  int n = blockIdx.x;
  int k = threadIdx.x;
  if (n < 1024) {
    const float* W = (n < 256) ? Wq : (n < 512) ? Wk : (n < 768) ? Wv : Wi;
    int nn = n & 255;
    WcatT[(size_t)n * 256 + k] = f2bf(W[(size_t)k * 256 + nn]);
    if (k == 0) {
      const float* b = (n < 256) ? bq : (n < 512) ? bk : (n < 768) ? bv : bi;
      bcat[n] = b[nn];
    }
  } else if (n < 1280) {
    int nn = n - 1024;
    WeT[(size_t)nn * 256 + k] = f2bf(We[(size_t)k * 256 + nn]);
  } else {
    int nn = n - 1280;
    WoT[(size_t)nn * 256 + k] = f2bf(Wo[(size_t)k * 256 + nn]);
  }
}

// ---------------------------------------------------------------------------
// Lean GEMM: C[M x Nn] = A(fp32, M x 256) @ B + bias. BT (Nn x 256) = B^T bf16.
// 128x128 tile, 4 waves 2x2, mfma(b,a,acc) so lanes hold 4 consecutive cols ->
// float4 C stores. Double-buffered LDS, reg prefetch, lgkmcnt-only barrier,
// 16B-chunk XOR swizzle (0 bank conflicts).
// ---------------------------------------------------------------------------
__global__ __launch_bounds__(256) void gemm3_k(
    const float* __restrict__ Afp, const u16* __restrict__ BT,
    const float* __restrict__ bias, float* __restrict__ C, int Nn)
{
  __shared__ u16 As[2][128 * 32];
  __shared__ u16 Bs[2][128 * 32];
  const int n0 = blockIdx.x * 128;
  const int m0 = blockIdx.y * 128;
  const int tid = threadIdx.x;
  const int w = tid >> 6, l = tid & 63;
  const int wr = w >> 1, wc = w & 1;
  const int fr = l & 15, hi = l >> 4;

  float4 pa[4];
  u16x8  pb[2];
  f32x4  acc[4][4] = {};

  auto loadstep = [&](int kt) {
#pragma unroll
    for (int i = 0; i < 4; ++i) {
      int j = tid + 256 * i;
      pa[i] = *(const float4*)(Afp + (size_t)(m0 + (j >> 3)) * 256 + kt * 32 + ((j & 7) << 2));
    }
#pragma unroll
    for (int i = 0; i < 2; ++i) {
      int j = tid + 256 * i;
      pb[i] = *(const u16x8*)(BT + (size_t)(n0 + (j >> 2)) * 256 + kt * 32 + ((j & 3) << 3));
    }
  };
  auto storestep = [&](int buf) {
#pragma unroll
    for (int i = 0; i < 4; ++i) {
      int j = tid + 256 * i;
      int row = j >> 3;
      int c16 = (j & 7) >> 1, half = j & 1;
      int swc = (c16 + ((row >> 1) & 3)) & 3;
      u16x4 u;
      u.x = f2bf(pa[i].x); u.y = f2bf(pa[i].y); u.z = f2bf(pa[i].z); u.w = f2bf(pa[i].w);
      *(u16x4*)&As[buf][row * 32 + swc * 8 + half * 4] = u;
    }
#pragma unroll
    for (int i = 0; i < 2; ++i) {
      int j = tid + 256 * i;
      int row = j >> 2;
      int swc = ((j & 3) + ((row >> 1) & 3)) & 3;
      *(u16x8*)&Bs[buf][row * 32 + swc * 8] = pb[i];
    }
  };

  loadstep(0);
  storestep(0);

#pragma unroll
  for (int kt = 0; kt < 8; ++kt) {
    if (kt < 7) loadstep(kt + 1);
    __builtin_amdgcn_sched_barrier(0);
    asm volatile("s_waitcnt lgkmcnt(0)" ::: "memory");
    __builtin_amdgcn_s_barrier();
    __builtin_amdgcn_sched_barrier(0);
    const int cur = kt & 1;
    bf16x8 a[4], b[4];
#pragma unroll
    for (int mi = 0; mi < 4; ++mi) {
      int rA = wr * 64 + mi * 16 + fr;
      int swc = (hi + ((rA >> 1) & 3)) & 3;
      a[mi] = *(const bf16x8*)&As[cur][rA * 32 + swc * 8];
    }
#pragma unroll
    for (int ni = 0; ni < 4; ++ni) {
      int rB = wc * 64 + ni * 16 + fr;
      int swc = (hi + ((rB >> 1) & 3)) & 3;
      b[ni] = *(const bf16x8*)&Bs[cur][rB * 32 + swc * 8];
    }
    // swapped operands: lane holds C[m = mi*16+fr][n = ni*16 + hi*4 + reg]
#pragma unroll
    for (int mi = 0; mi < 4; ++mi)
#pragma unroll
      for (int ni = 0; ni < 4; ++ni)
        acc[mi][ni] = __builtin_amdgcn_mfma_f32_16x16x32_bf16(
            b[ni], a[mi], acc[mi][ni], 0, 0, 0);
    if (kt < 7) storestep((kt + 1) & 1);
  }

  // C write: float4 per (mi,ni)
#pragma unroll
  for (int mi = 0; mi < 4; ++mi) {
    int row = m0 + wr * 64 + mi * 16 + fr;
#pragma unroll
    for (int ni = 0; ni < 4; ++ni) {
      int col = n0 + wc * 64 + ni * 16 + hi * 4;
      float4 bv = *(const float4*)&bias[col];
      f32x4 v = acc[mi][ni];
      float4 o;
      o.x = v[0] + bv.x; o.y = v[1] + bv.y; o.z = v[2] + bv.z; o.w = v[3] + bv.w;
      *(float4*)&C[(size_t)row * Nn + col] = o;
    }
  }
}

// ---------------------------------------------------------------------------
// CSR build
// ---------------------------------------------------------------------------
__global__ __launch_bounds__(256) void hist_k(const int* __restrict__ src, int* __restrict__ deg)
{
  int e = blockIdx.x * 256 + threadIdx.x;
  if (e < N_EDGES) atomicAdd(&deg[src[e]], 1);
}

__global__ __launch_bounds__(1024) void scan_k(const int* __restrict__ deg,
                                               int* __restrict__ rowstart,
                                               int* __restrict__ cursor)
{
  __shared__ int s[1024];
  int tid = threadIdx.x;
  int4 v = ((const int4*)deg)[tid];
  int sum = v.x + v.y + v.z + v.w;
  s[tid] = sum;
  __syncthreads();
  for (int off = 1; off < 1024; off <<= 1) {
    int t = (tid >= off) ? s[tid - off] : 0;
    __syncthreads();
    s[tid] += t;
    __syncthreads();
  }
  int excl = s[tid] - sum;
  int r0 = excl, r1 = excl + v.x, r2 = r1 + v.y, r3 = r2 + v.z;
  rowstart[4 * tid + 0] = r0; cursor[4 * tid + 0] = r0;
  rowstart[4 * tid + 1] = r1; cursor[4 * tid + 1] = r1;
  rowstart[4 * tid + 2] = r2; cursor[4 * tid + 2] = r2;
  rowstart[4 * tid + 3] = r3; cursor[4 * tid + 3] = r3;
  if (tid == 1023) rowstart[4096] = r3 + v.w;
}

__global__ __launch_bounds__(256) void scatter_k(const int* __restrict__ src,
                                                 int* __restrict__ cursor,
                                                 int* __restrict__ csr)
{
  int e = blockIdx.x * 256 + threadIdx.x;
  if (e < N_EDGES) {
    int p = atomicAdd(&cursor[src[e]], 1);
    csr[p] = e;
  }
}

// ---------------------------------------------------------------------------
// Fused per-node kernel: edge logits + sparse softmax + V aggregation.
// One block (256 thr, 4 waves) per node. Q_i in registers (float4/lane);
// per edge: stream Ef row (HBM) + K_tgt row (L2/L3), 8-lane/head reduce.
// ---------------------------------------------------------------------------
__global__ __launch_bounds__(256) void node_attn_k(
    const float* __restrict__ QKVI, const float* __restrict__ Ef,
    const int* __restrict__ rowstart, const int* __restrict__ csr,
    const int* __restrict__ tgt, float* __restrict__ agg)
{
  __shared__ int   s_eid[MAXDEG];
  __shared__ int   s_tgt[MAXDEG];
  __shared__ float s_sc[HEADS][MAXDEGP];   // scores, then weights in-place
  __shared__ unsigned char s_alive[MAXDEG];
  __shared__ float s_self[8];
  __shared__ float s_wself[8];

  const float scl = 0.17677669529663687f;
  int i = blockIdx.x;
  int base = rowstart[i];
  int deg = rowstart[i + 1] - base;
  if (deg > MAXDEG) deg = MAXDEG;
  int tid = threadIdx.x;
  int w = tid >> 6, l = tid & 63;
  int h = tid >> 5, d = tid & 31;

  for (int t = tid; t < deg; t += 256) {
    int e = csr[base + t];
    s_eid[t] = e;
    s_tgt[t] = tgt[e];
  }
  __syncthreads();

  // Q_i: lane l holds dims 4l..4l+3 (head = l>>3)
  float4 q4 = *(const float4*)&QKVI[(size_t)i * 1024 + 4 * l];

  // self score (wave 0): Q_i . K_i per head
  if (w == 0) {
    float4 k4 = *(const float4*)&QKVI[(size_t)i * 1024 + 256 + 4 * l];
    float c = dot4(q4, k4);
#pragma unroll
    for (int off = 1; off <= 4; off <<= 1) c += __shfl_xor(c, off);
    if ((l & 7) == 0) s_self[l >> 3] = c * scl;
  }

  // edge logits: waves split edges; logit = ef.(q+k) + q.k per head
  for (int t = w; t < deg; t += 4) {
    int e = s_eid[t], tt = s_tgt[t];
    float4 ef = *(const float4*)&Ef[(size_t)e * 256 + 4 * l];
    float4 k4 = *(const float4*)&QKVI[(size_t)tt * 1024 + 256 + 4 * l];
    float c = dot4(q4, ef) + dot4(ef, k4) + dot4(q4, k4);
#pragma unroll
    for (int off = 1; off <= 4; off <<= 1) c += __shfl_xor(c, off);
    if ((l & 7) == 0) s_sc[l >> 3][t] = c * scl;
  }

  // dedup (keep max eid per tgt), drop self-target
  for (int t = tid; t < deg; t += 256) {
    int tt = s_tgt[t], ee = s_eid[t];
    bool alive = (tt != i);
    if (alive)
      for (int u = 0; u < deg; ++u)
        if (s_tgt[u] == tt && s_eid[u] > ee) { alive = false; break; }
    s_alive[t] = alive ? 1 : 0;
  }
  __syncthreads();

  // softmax: 32 lanes per head, in-place weights
  {
    float m = s_self[h];
    for (int t = d; t < deg; t += 32)
      if (s_alive[t]) m = fmaxf(m, s_sc[h][t]);
#pragma unroll
    for (int off = 16; off > 0; off >>= 1) m = fmaxf(m, __shfl_xor(m, off, 32));
    float lsum = 0.f;
    for (int t = d; t < deg; t += 32) {
      float wv = s_alive[t] ? expf(s_sc[h][t] - m) : 0.f;
      s_sc[h][t] = wv;
      lsum += wv;
    }
#pragma unroll
    for (int off = 16; off > 0; off >>= 1) lsum += __shfl_xor(lsum, off, 32);
    float wself = expf(s_self[h] - m);
    float inv = 1.f / (lsum + wself);
    if (d == 0) s_wself[h] = wself * inv;
    for (int t = d; t < deg; t += 32) s_sc[h][t] *= inv;
  }
  __syncthreads();

  // aggregate V (cols 512..767 of QKVI); col = tid -> coalesced
  int col = tid;
  float accv = s_wself[h] * QKVI[(size_t)i * 1024 + 512 + col];
  for (int t = 0; t < deg; ++t)
    if (s_alive[t])
      accv += s_sc[h][t] * QKVI[(size_t)s_tgt[t] * 1024 + 512 + col];
  agg[(size_t)i * 256 + col] = accv;
}

// ---------------------------------------------------------------------------
// LayerNorm(x_proj + preo)
// ---------------------------------------------------------------------------
__global__ __launch_bounds__(256) void ln_k(
    const float* __restrict__ QKVI, const float* __restrict__ preo,
    const float* __restrict__ g, const float* __restrict__ b,
    float* __restrict__ out)
{
  int i = blockIdx.x, c = threadIdx.x;
  float v = QKVI[(size_t)i * 1024 + 768 + c] + preo[(size_t)i * 256 + c];
  float s1 = v, s2 = v * v;
#pragma unroll
  for (int off = 32; off > 0; off >>= 1) {
    s1 += __shfl_xor(s1, off, 64);
    s2 += __shfl_xor(s2, off, 64);
  }
  __shared__ float r1[4], r2[4];
  int w = c >> 6;
  if ((c & 63) == 0) { r1[w] = s1; r2[w] = s2; }
  __syncthreads();
  s1 = r1[0] + r1[1] + r1[2] + r1[3];
  s2 = r2[0] + r2[1] + r2[2] + r2[3];
  float mu  = s1 * (1.0f / 256.0f);
  float var = s2 * (1.0f / 256.0f) - mu * mu;
  out[(size_t)i * 256 + c] = (v - mu) * rsqrtf(var + 1e-5f) * g[c] + b[c];
}

// ---------------------------------------------------------------------------
extern "C" void kernel_launch(void* const* d_in, const int* in_sizes, int n_in,
                              void* d_out, int out_size, void* d_ws, size_t ws_size,
                              hipStream_t stream) {
  (void)in_sizes; (void)n_in; (void)out_size; (void)ws_size;
  const float* x  = (const float*)d_in[0];
  const int*   ei = (const int*)d_in[1];
  const float* ea = (const float*)d_in[2];
  const float* Wq = (const float*)d_in[3];  const float* bq = (const float*)d_in[4];
  const float* Wk = (const float*)d_in[5];  const float* bk = (const float*)d_in[6];
  const float* Wv = (const float*)d_in[7];  const float* bv = (const float*)d_in[8];
  const float* We = (const float*)d_in[9];  const float* be = (const float*)d_in[10];
  const float* Wo = (const float*)d_in[11]; const float* bo = (const float*)d_in[12];
  const float* Wi = (const float*)d_in[13]; const float* bi = (const float*)d_in[14];
  const float* lng = (const float*)d_in[15]; const float* lnb = (const float*)d_in[16];

  const int* src = ei;
  const int* tgt = ei + N_EDGES;

  char* ws = (char*)d_ws;
  u16*   WcatT   = (u16*)(ws + 0);              //  512 KB
  u16*   WeT     = (u16*)(ws + 524288);         //  128 KB
  u16*   WoT     = (u16*)(ws + 655360);         //  128 KB
  float* bcat    = (float*)(ws + 786432);       //    4 KB
  float* QKVI    = (float*)(ws + 790528);       //   16 MB
  int*   deg     = (int*)(ws + 17567744);       //   16 KB
  int*   rowstart= (int*)(ws + 17584128);       //   16.25 KB
  int*   cursor  = (int*)(ws + 17600768);       //   16 KB
  int*   csr     = (int*)(ws + 17617152);       //  512 KB
  float* agg     = (float*)(ws + 18141440);     //    4 MB
  float* preo    = (float*)(ws + 22335744);     //    4 MB

  float* outN = (float*)d_out;
  float* outE = (float*)d_out + (size_t)N_NODES * DIM;

  hipMemsetAsync(deg, 0, N_NODES * sizeof(int), stream);

  prep_w_k<<<1536, 256, 0, stream>>>(Wq, Wk, Wv, Wi, We, Wo, bq, bk, bv, bi,
                                     WcatT, WeT, WoT, bcat);

  hist_k<<<N_EDGES / 256, 256, 0, stream>>>(src, deg);
  scan_k<<<1, 1024, 0, stream>>>(deg, rowstart, cursor);
  scatter_k<<<N_EDGES / 256, 256, 0, stream>>>(src, cursor, csr);

  // QKVI = x @ [Wq|Wk|Wv|Wi] + bcat
  gemm3_k<<<dim3(8, 32), 256, 0, stream>>>(x, WcatT, bcat, QKVI, 1024);

  // edge_out = edge_attr @ We + be   (pure, no fusion)
  gemm3_k<<<dim3(2, 1024), 256, 0, stream>>>(ea, WeT, be, outE, 256);

  // fused logits + softmax + V aggregation
  node_attn_k<<<N_NODES, 256, 0, stream>>>(QKVI, outE, rowstart, csr, tgt, agg);

  // preo = agg @ Wo + bo
  gemm3_k<<<dim3(2, 32), 256, 0, stream>>>(agg, WoT, bo, preo, 256);

  ln_k<<<N_NODES, 256, 0, stream>>>(QKVI, preo, lng, lnb, outN);
}